// Round 10
// baseline (342.256 us; speedup 1.0000x reference)
//
#include <hip/hip_runtime.h>
#include <hip/hip_bf16.h>

typedef __bf16 bf16_t;
typedef __attribute__((ext_vector_type(8))) __bf16 bf16x8;
typedef __attribute__((ext_vector_type(4))) float f32x4;
typedef __attribute__((ext_vector_type(4))) int   i32x4;

#define C_IN   256
#define C_OUT  512
#define HW     3136      // 56*56
#define NB     32        // batch
#define HP     58        // 56 + 2 halo
#define NQBLK  36864     // (512*256*9)/32 quant blocks

// conv-GEMM: BM=256(co) x BN=224(4 img rows) x BK=64; NT=36 tiles (9 pos x 4 ci-chunks)
#define NT   36
#define NWG  896         // 448 px-bands (32 img x 14) x 2 co-blocks

typedef const __attribute__((address_space(1))) unsigned int gu32;
typedef __attribute__((address_space(3))) unsigned int lu32;
__device__ __forceinline__ void gl16(const void* g, void* l) {
    __builtin_amdgcn_global_load_lds((gu32*)g, (lu32*)l, 16, 0, 0);
}
#define BAR()    __builtin_amdgcn_s_barrier()
#define PRIO(x)  __builtin_amdgcn_s_setprio(x)
#define SCHED0() __builtin_amdgcn_sched_barrier(0)

__device__ __forceinline__ bf16x8 asbf(i32x4 v) {
    union { i32x4 a; bf16x8 b; } u; u.a = v; return u.b;
}
__device__ __forceinline__ f32x4 MF(i32x4 a, i32x4 b, f32x4 c) {
    return __builtin_amdgcn_mfma_f32_16x16x32_bf16(asbf(a), asbf(b), c, 0, 0, 0);
}

// ---------------- kernel 1: 6-bit fake-quant + repack to Wt[p][co][ci] (bf16) ----------------
__global__ void k_dequant(const float* __restrict__ w, bf16_t* __restrict__ wt) {
    int b = blockIdx.x * blockDim.x + threadIdx.x;
    if (b >= NQBLK) return;
    const float* src = w + (size_t)b * 32;
    float v[32];
    float amax = 0.f;
    #pragma unroll
    for (int i = 0; i < 32; i += 4) {
        float4 t = *reinterpret_cast<const float4*>(src + i);
        v[i] = t.x; v[i+1] = t.y; v[i+2] = t.z; v[i+3] = t.w;
        amax = fmaxf(amax, fmaxf(fmaxf(fabsf(t.x), fabsf(t.y)),
                                 fmaxf(fabsf(t.z), fabsf(t.w))));
    }
    float scale = amax / 31.0f;
    if (scale == 0.f) scale = 1.f;
    #pragma unroll
    for (int i = 0; i < 32; i++) {
        float q = rintf(v[i] / scale);            // jnp.round = RNE = rintf
        q = fminf(31.f, fmaxf(-32.f, q));
        float dq = q * scale;
        int flat = b * 32 + i;                    // flat over OIHW
        int p    = flat % 9;
        int rest = flat / 9;
        int ci   = rest & 255;
        int co   = rest >> 8;
        wt[((size_t)(p * C_OUT + co) << 8) + ci] = (bf16_t)dq;
    }
}

// ---------------- kernel 1b: zero the 1-pixel halo ring of xT ----------------
__global__ void k_halo_zero(bf16_t* __restrict__ xT) {
    int idx = blockIdx.x * 256 + threadIdx.x;
    if (idx >= NB * 228 * 32) return;
    int c8 = idx & 31;
    int t  = idx >> 5;
    int p  = t % 228;
    int n  = t / 228;
    int hh, ww;
    if      (p < 58)  { hh = 0;           ww = p; }
    else if (p < 116) { hh = 57;          ww = p - 58; }
    else if (p < 172) { hh = p - 116 + 1; ww = 0; }
    else              { hh = p - 172 + 1; ww = 57; }
    size_t e = (((size_t)n * HP + hh) * HP + ww) * C_IN + c8 * 8;
    *reinterpret_cast<uint4*>(xT + e) = make_uint4(0, 0, 0, 0);
}

// ------- kernel 2: x NCHW fp32 -> halo-padded NHWC bf16 (xT[n][58][58][ci]) -------
__global__ void k_x_nhwc(const float* __restrict__ x, bf16_t* __restrict__ xT) {
    __shared__ float tile[64][65];
    const int n   = blockIdx.z;
    const int cb  = blockIdx.y * 64;
    const int hwb = blockIdx.x * 64;
    const int t   = threadIdx.x;

    const int col = t & 63;
    const int r0  = t >> 6;
    #pragma unroll
    for (int k = 0; k < 16; k++) {
        int r = r0 * 16 + k;
        tile[r][col] = x[((size_t)(n * C_IN + cb + r)) * HW + hwb + col];
    }
    __syncthreads();

    const int j  = t >> 2;
    const int co = (t & 3) * 16;
    const int hw = hwb + j;
    const int hh = hw / 56, ww = hw - hh * 56;
    __align__(16) bf16_t vals[16];
    #pragma unroll
    for (int k = 0; k < 16; k++)
        vals[k] = (bf16_t)tile[co + k][j];
    bf16_t* dst = xT + (((size_t)n * HP + hh + 1) * HP + (ww + 1)) * C_IN + cb + co;
    *reinterpret_cast<uint4*>(dst)     = *reinterpret_cast<uint4*>(&vals[0]);
    *reinterpret_cast<uint4*>(dst + 8) = *reinterpret_cast<uint4*>(&vals[8]);
}

// ------------- kernel 3: implicit-GEMM conv, full-tile-flight pipeline -------------
// Geometry = R9: 8 waves 4(M)x2(N), wave 64(co)x112(px), acc[4][7]; K-tile = 64 ci of one pos.
// LDS: As[2][256][64] (64KB dbl) + Bs[3][224][64] (84KB TRIPLE) = 148 KB.
// vs R9: (1) B triple-buffered: B(t+2) staged during t -> drained end-of-t+1 -> read t+2:
//   a FULL tile (~4000cyc) of HBM latency cover (xT misses were the end-of-tile stall).
// (2) A double suffices: A(t) frags are in regs since t-1, so As[t&1] is writable during t;
//   A(t+2) staged j0/j1 of t, drained end-of-t (Wt is L2-resident, ~200cyc, free).
// (3) b0/b1 of t+1 pre-read at j5/j6 of t from Bs[(t+1)%3] (resident since end of t-1)
//   into DEDICATED T0/T1 reg pairs -> no tile-start read burst/stall.
// Buffer safety during tile t: reads touch As[(t+1)&1], Bs[t%3], Bs[(t+1)%3];
//   writes go to As[t&1], Bs[(t+2)%3] -- disjoint. One barrier per tile.
// End-of-tile wait: vmcnt(4) keeps B(t+2) (4 newest, issued j2/j3) in flight; drains
//   A(t+2) (issued j0/j1, L2). Tail (t+2>=NT): vmcnt(0).
// LGKM FIFO ledger (verified trace; carry = [AC30,AC31,T0x2,T1x2] = 6 outstanding):
//   j0:+S0(b2)        ->8;  LGKM(4)  drains AC30/31,T0 -> MFMA8(b0=T0)
//   j1:+S1(b3),+AN0/1 ->8;  LGKM(6)  drains T1         -> MFMA8(b1=T1)
//   j2:+S2(b4),+AN2/3 ->10; LGKM(8)  drains S0         -> MFMA8(b2=S0)
//   j3:+S0(b5),+AN4/5 ->12; LGKM(10) drains S1         -> MFMA8(b3=S1)
//   j4:+S1(b6),+AN6/7 ->14; LGKM(10) drains AN0/1,S2   -> MFMA8(b4=S2)
//   j5:+T0(b0')       ->12; LGKM(8)  drains AN2/3,S0   -> MFMA8(b5=S0)
//   j6:+T1(b1')       ->10; LGKM(6)  drains AN4/5,S1   -> MFMA8(b6=S1)
//   carry-out = [AN30,AN31,T0x2,T1x2] = 6 ✓.  t=35's AN/T reads hit stale (landed) LDS: safe.
// XOR swizzle chunk^=row&7 on 128B rows (0 conflicts, R3/R6/R8/R9); pre-swizzled global source.
__global__ __launch_bounds__(512, 2) void k_conv_gemm(
    const bf16_t* __restrict__ xT, const bf16_t* __restrict__ wt,
    const float* __restrict__ bias, float* __restrict__ out)
{
    __shared__ __align__(16) bf16_t As[2][256][64];   // 64 KB
    __shared__ __align__(16) bf16_t Bs[3][224][64];   // 84 KB

    const int tid  = threadIdx.x;
    const int lane = tid & 63;
    const int wid  = tid >> 6;
    const int wr   = wid >> 1;      // 0..3 -> co slice of 64
    const int wc   = wid & 1;       // 0..1 -> px slice of 112

    // bijective XCD swizzle: 896 = 8 x 112; co-fastest within chunk
    const int orig  = blockIdx.x;
    const int wgid  = (orig & 7) * 112 + (orig >> 3);
    const int co0   = (wgid & 1) * 256;
    const int sband = wgid >> 1;                 // 0..447
    const int nimg  = sband / 14;
    const int R0    = (sband - nimg * 14) * 4;   // first output row of band

    // ---- staging geometry: per 64-row issue, thread covers row tid>>3, 16B chunk tid&7
    const int trow = tid >> 3;                   // 0..63
    const int lcx  = (tid & 7) ^ (trow & 7);     // pre-swizzled source chunk (key = row&7)

    const bf16_t* pA[4];
    const bf16_t* pB[4];
    #pragma unroll
    for (int i = 0; i < 4; i++) {
        pA[i] = wt + ((size_t)(co0 + i * 64 + trow) << 8) + lcx * 8;
        int r  = i * 64 + trow;
        int br = r / 56, bc = r - br * 56;
        pB[i] = xT + (((size_t)nimg * HP + R0 + br + 1) * HP + (bc + 1)) * C_IN + lcx * 8;
    }

    auto stageA2 = [&](int slot, int tk, int part) {   // part0: rows 0-127, part1: 128-255
        const size_t off = ((size_t)(tk >> 2) << 17) + ((tk & 3) << 6);
        bf16_t* dst = &As[slot][0][0] + wid * 512;
        if (part == 0) { gl16(pA[0] + off, dst);        gl16(pA[1] + off, dst + 4096); }
        else           { gl16(pA[2] + off, dst + 8192); gl16(pA[3] + off, dst + 12288); }
    };
    auto stageB2 = [&](int buf, int tk, int part) {    // part0: rows 0-127, part1: 128-223
        const int p  = tk >> 2;
        const int q3 = p / 3;
        const int off = ((q3 - 1) * HP + (p - q3 * 3) - 1) * C_IN + ((tk & 3) << 6);
        bf16_t* dst = &Bs[buf][0][0] + wid * 512;
        if (part == 0) { gl16(pB[0] + off, dst);        gl16(pB[1] + off, dst + 4096); }
        else           { gl16(pB[2] + off, dst + 8192);
                         if (tid < 256) gl16(pB[3] + off, dst + 12288); }
    };

    // ---- LDS byte addresses for asm ds_read (swizzle key = rl&7, invariant over j,m) ----
    const int rl = lane & 15;
    const int kg = lane >> 4;
    const unsigned asBase = (unsigned)(uintptr_t)&As[0][0][0];
    const unsigned bsBase = (unsigned)(uintptr_t)&Bs[0][0][0];
    const unsigned aAddr0 = asBase + (unsigned)((wr * 64 + rl) * 128 + ((kg       ^ (rl & 7)) * 16));
    const unsigned aAddr1 = asBase + (unsigned)((wr * 64 + rl) * 128 + (((4 + kg) ^ (rl & 7)) * 16));
    const unsigned bAddr0 = bsBase + (unsigned)((wc * 112 + rl) * 128 + ((kg       ^ (rl & 7)) * 16));
    const unsigned bAddr1 = bsBase + (unsigned)((wc * 112 + rl) * 128 + (((4 + kg) ^ (rl & 7)) * 16));

    f32x4 acc[4][7];
    #pragma unroll
    for (int m = 0; m < 4; m++)
        #pragma unroll
        for (int j = 0; j < 7; j++)
            acc[m][j] = f32x4{0.f, 0.f, 0.f, 0.f};

#define RD2(D0, D1, A0, A1, OFFS) \
    asm volatile("ds_read_b128 %0, %2 offset:" OFFS "\n\t" \
                 "ds_read_b128 %1, %3 offset:" OFFS \
                 : "=v"(D0), "=v"(D1) : "v"(A0), "v"(A1));
#define LGKM(N) asm volatile("s_waitcnt lgkmcnt(" N ")" ::: "memory"); SCHED0();
#define MFMA8(AA, J, X0, X1) \
    PRIO(1); \
    acc[0][J] = MF(AA##00, X0, acc[0][J]); acc[0][J] = MF(AA##01, X1, acc[0][J]); \
    acc[1][J] = MF(AA##10, X0, acc[1][J]); acc[1][J] = MF(AA##11, X1, acc[1][J]); \
    acc[2][J] = MF(AA##20, X0, acc[2][J]); acc[2][J] = MF(AA##21, X1, acc[2][J]); \
    acc[3][J] = MF(AA##30, X0, acc[3][J]); acc[3][J] = MF(AA##31, X1, acc[3][J]); \
    PRIO(0);

// TILE: AC = current A regs, AN = next A regs, T = tile index,
//       BC/BNX/BST = Bs buffer index for t%3 / (t+1)%3 / (t+2)%3
#define TILE(AC, AN, T, BC, BNX, BST) do {                                    \
    const unsigned bT0 = bAddr0 + (unsigned)(BC) * 28672u;                    \
    const unsigned bT1 = bAddr1 + (unsigned)(BC) * 28672u;                    \
    const unsigned nA0 = aAddr0 + (unsigned)(((T) + 1) & 1) * 32768u;         \
    const unsigned nA1 = aAddr1 + (unsigned)(((T) + 1) & 1) * 32768u;         \
    const unsigned pT0 = bAddr0 + (unsigned)(BNX) * 28672u;                   \
    const unsigned pT1 = bAddr1 + (unsigned)(BNX) * 28672u;                   \
    /* j0 */                                                                  \
    RD2(S00, S01, bT0, bT1, "4096");                                          \
    if ((T) + 2 < NT) stageA2((T) & 1, (T) + 2, 0);                           \
    LGKM("4");  MFMA8(AC, 0, T00, T01);                                       \
    /* j1 */                                                                  \
    RD2(S10, S11, bT0, bT1, "6144");                                          \
    RD2(AN##00, AN##01, nA0, nA1, "0");                                       \
    if ((T) + 2 < NT) stageA2((T) & 1, (T) + 2, 1);                           \
    LGKM("6");  MFMA8(AC, 1, T10, T11);                                       \
    /* j2 */                                                                  \
    RD2(S20, S21, bT0, bT1, "8192");                                          \
    RD2(AN##10, AN##11, nA0, nA1, "2048");                                    \
    if ((T) + 2 < NT) stageB2((BST), (T) + 2, 0);                             \
    LGKM("8");  MFMA8(AC, 2, S00, S01);                                       \
    /* j3 */                                                                  \
    RD2(S00, S01, bT0, bT1, "10240");                                         \
    RD2(AN##20, AN##21, nA0, nA1, "4096");                                    \
    if ((T) + 2 < NT) stageB2((BST), (T) + 2, 1);                             \
    LGKM("10"); MFMA8(AC, 3, S10, S11);                                       \
    /* j4 */                                                                  \
    RD2(S10, S11, bT0, bT1, "12288");                                         \
    RD2(AN##30, AN##31, nA0, nA1, "6144");                                    \
    LGKM("10"); MFMA8(AC, 4, S20, S21);                                       \
    /* j5: pre-read b0(T+1) */                                                \
    RD2(T00, T01, pT0, pT1, "0");                                             \
    LGKM("8");  MFMA8(AC, 5, S00, S01);                                       \
    /* j6: pre-read b1(T+1) */                                                \
    RD2(T10, T11, pT0, pT1, "2048");                                          \
    LGKM("6");  MFMA8(AC, 6, S10, S11);                                       \
    if ((T) + 2 < NT)                                                         \
        asm volatile("s_waitcnt vmcnt(4)" ::: "memory");                      \
    else                                                                      \
        asm volatile("s_waitcnt vmcnt(0)" ::: "memory");                      \
    BAR();                                                                    \
    SCHED0();                                                                 \
} while (0)

    i32x4 Ea00, Ea01, Ea10, Ea11, Ea20, Ea21, Ea30, Ea31;
    i32x4 Eb00, Eb01, Eb10, Eb11, Eb20, Eb21, Eb30, Eb31;
    i32x4 S00, S01, S10, S11, S20, S21;
    i32x4 T00, T01, T10, T11;

    // ---- prologue: stage A(0)->As[0], A(1)->As[1], B(0)->Bs[0], B(1)->Bs[1]; drain; BAR;
    //      preload Ea = A(0) frags, T0/T1 = b0/b1 of tile 0; leave 6 in lgkm flight ----
    stageA2(0, 0, 0); stageA2(0, 0, 1);
    stageA2(1, 1, 0); stageA2(1, 1, 1);
    stageB2(0, 0, 0); stageB2(0, 0, 1);
    stageB2(1, 1, 0); stageB2(1, 1, 1);
    asm volatile("s_waitcnt vmcnt(0)" ::: "memory");
    BAR();
    SCHED0();
    RD2(Ea00, Ea01, aAddr0, aAddr1, "0");
    RD2(Ea10, Ea11, aAddr0, aAddr1, "2048");
    RD2(Ea20, Ea21, aAddr0, aAddr1, "4096");
    RD2(Ea30, Ea31, aAddr0, aAddr1, "6144");
    RD2(T00, T01, bAddr0, bAddr1, "0");
    RD2(T10, T11, bAddr0, bAddr1, "2048");
    LGKM("6");   // leave [Ea30,Ea31,T0x2,T1x2] in flight = loop carry-in

    #pragma unroll 1
    for (int t = 0; t < NT; t += 6) {
        TILE(Ea, Eb, t + 0, 0, 1, 2);
        TILE(Eb, Ea, t + 1, 1, 2, 0);
        TILE(Ea, Eb, t + 2, 2, 0, 1);
        TILE(Eb, Ea, t + 3, 0, 1, 2);
        TILE(Ea, Eb, t + 4, 1, 2, 0);
        TILE(Eb, Ea, t + 5, 2, 0, 1);
    }
    // drain the 6 dangling reads before epilogue register reuse
    asm volatile("s_waitcnt lgkmcnt(0)" ::: "memory");
    SCHED0();

#undef RD2
#undef LGKM
#undef MFMA8
#undef TILE

    // ---- epilogue: D row(co) = m*16 + 4*(lane>>4)+i, col(px) = wc*112 + j*16 + rl ----
    int hw_off[7];
    #pragma unroll
    for (int j = 0; j < 7; j++) {
        int nn = wc * 112 + j * 16 + rl;
        int br = nn / 56, bc = nn - br * 56;
        hw_off[j] = (R0 + br) * 56 + bc;
    }
    const size_t obase = (size_t)nimg * C_OUT * HW;
    #pragma unroll
    for (int m = 0; m < 4; m++) {
        int cob = co0 + wr * 64 + m * 16 + ((lane >> 4) << 2);
        #pragma unroll
        for (int i = 0; i < 4; i++) {
            int co = cob + i;
            float bv = bias[co];
            float* orow = out + obase + (size_t)co * HW;
            #pragma unroll
            for (int j = 0; j < 7; j++)
                orow[hw_off[j]] = acc[m][j][i] + bv;
        }
    }
}

extern "C" void kernel_launch(void* const* d_in, const int* in_sizes, int n_in,
                              void* d_out, int out_size, void* d_ws, size_t ws_size,
                              hipStream_t stream) {
    const float* x    = (const float*)d_in[0];
    const float* w    = (const float*)d_in[1];
    const float* bias = (const float*)d_in[2];
    float* out = (float*)d_out;

    // workspace: xT halo-padded NHWC bf16 (32*58*58*256*2 = 55.1 MB) then Wt (2.4 MB)
    bf16_t* xT = (bf16_t*)d_ws;
    bf16_t* wt = (bf16_t*)((char*)d_ws + (size_t)NB * HP * HP * C_IN * 2);

    k_halo_zero<<<dim3((NB * 228 * 32 + 255) / 256), dim3(256), 0, stream>>>(xT);
    k_x_nhwc<<<dim3(49, 4, NB), dim3(256), 0, stream>>>(x, xT);
    k_dequant<<<dim3((NQBLK + 255) / 256), dim3(256), 0, stream>>>(w, wt);
    k_conv_gemm<<<dim3(NWG), dim3(512), 0, stream>>>(xT, wt, bias, out);
}